// Round 2
// baseline (18299.294 us; speedup 1.0000x reference)
//
#include <hip/hip_runtime.h>
#include <hip/hip_bf16.h>

typedef __attribute__((ext_vector_type(8))) short short8;
typedef __attribute__((ext_vector_type(4))) float floatx4;
typedef unsigned short u16;

// B=128, T=256, D=6, H=512, 4H=2048, NC=4, PS=12

__device__ __forceinline__ u16 f2b(float f){
  union { float fl; unsigned u; } v; v.fl = f;
  unsigned r = v.u + 0x7fffu + ((v.u >> 16) & 1u);   // RNE bf16
  return (u16)(r >> 16);
}

// ---------------- prep kernels ----------------

// (2048,512) fp32 -> bf16, rows reordered r=gate*512+j -> r'=j*4+gate
__global__ void reorder_w_k(const float* __restrict__ W, u16* __restrict__ out){
  int idx = blockIdx.x*256 + threadIdx.x;       // 2048*512
  int r = idx >> 9, k = idx & 511;
  int rp = ((r & 511) << 2) | (r >> 9);
  out[rp*512 + k] = f2b(W[idx]);
}

// enc_Wih0 (2048,6) -> (2048,32) bf16 zero-padded, rows reordered
__global__ void prep_wx0_k(const float* __restrict__ W, u16* __restrict__ out){
  int idx = blockIdx.x*256 + threadIdx.x;       // 2048*32
  int r = idx >> 5, k = idx & 31;
  int rp = ((r & 511) << 2) | (r >> 9);
  out[rp*32 + k] = (k < 6) ? f2b(W[r*6 + k]) : (u16)0;
}

__global__ void prep_bias_k(const float* __restrict__ bih, const float* __restrict__ bhh,
                            float* __restrict__ out){
  int r = blockIdx.x*256 + threadIdx.x;         // 2048
  int rp = ((r & 511) << 2) | (r >> 9);
  out[rp] = bih[r] + bhh[r];
}

// x (B,T,6) fp32 -> Xb (T,B,32) bf16 zero-padded
__global__ void prep_x_k(const float* __restrict__ x, u16* __restrict__ out){
  int idx = blockIdx.x*256 + threadIdx.x;       // 256*128*32
  int t = idx >> 12; int rem = idx & 4095; int b = rem >> 5; int k = rem & 31;
  out[idx] = (k < 6) ? f2b(x[(b*256 + t)*6 + k]) : (u16)0;
}

// ---------------- persistent LSTM kernel ----------------

struct PK {
  const u16 *Xb, *Wx0, *W0hh, *W1ih, *W1hh, *Wd0ih, *Wd0hh, *Wd1ih, *Wd1hh;
  const float *Bs;              // 4x2048 gate-interleaved biases: enc0,enc1,dec0,dec1
  u16 *h0b, *h1b;               // bf16 ping-pong h buffers [2][128][512]
  unsigned *flags;              // [0..7]=layer0 per-mt, [8..15]=layer1 per-mt (monotone)
  const float *fcW, *fcb, *clsW, *clsb, *regW, *regb;
  float *out;
};

// wg mapping: xcd = w&7, q = w>>3; layer = q>>5; mt = q&7; nt = xcd*4 + ((q&31)>>3)
// Each XCD owns a fixed 256-column slice of all weight matrices -> L2-resident.
// Flags: monotone counters, 32 producers per (layer, mt) per slot.
// Encoder: layer0 slot t produces h0[t]; layer1 slot t processes u=t-1.
// Decoder continues parity sequence: dec l0 slot s reads h1b[ps],h0b[ps] writes h0b[1-ps],
// dec l1 reads h0b[1-ps],h1b[ps] writes h1b[1-ps], ps=(s&1)^1.

__global__ __launch_bounds__(256, 2) void persist_k(PK p){
  const int tid  = threadIdx.x;
  const int w    = blockIdx.x;
  const int xcd  = w & 7;
  const int q    = w >> 3;
  const int layer= q >> 5;
  const int mt   = q & 7;
  const int nt   = xcd*4 + ((q & 31) >> 3);
  const int wave = tid >> 6, lane = tid & 63;
  const int lrow = lane & 15, kq = lane >> 4;
  const int m    = mt*16 + lrow;
  const int nb   = nt*64 + wave*16 + lrow;
  const int bl   = tid & 15, jl = tid >> 4;
  const int HB   = 128*512;
  __shared__ float g[16][65];
  unsigned* f0 = p.flags + mt;
  unsigned* f1 = p.flags + 8 + mt;
  float creg = 0.f;   // this thread's cell state, lives in a register for the whole run

  auto waits = [&](unsigned* fa, unsigned va, unsigned* fb, unsigned vb){
    if (tid == 0){
      while (__hip_atomic_load(fa, __ATOMIC_RELAXED, __HIP_MEMORY_SCOPE_AGENT) < va)
        __builtin_amdgcn_s_sleep(1);
      while (__hip_atomic_load(fb, __ATOMIC_RELAXED, __HIP_MEMORY_SCOPE_AGENT) < vb)
        __builtin_amdgcn_s_sleep(1);
      __threadfence();   // acquire: invalidate stale L1/L2 before reading h
    }
    __syncthreads();
  };
  auto release = [&](unsigned* f){
    __syncthreads();     // drain this wg's h stores (vmcnt) on every wave
    if (tid == 0){
      __threadfence();   // release: write back dirty L2 so other XCDs see h
      __hip_atomic_fetch_add(f, 1u, __ATOMIC_RELAXED, __HIP_MEMORY_SCOPE_AGENT);
    }
  };
  auto step = [&](const u16* A1, int K1, const u16* W1,
                  const u16* A2, const u16* W2,
                  const float* bias, u16* hb) -> float {
    floatx4 acc = {0.f, 0.f, 0.f, 0.f};
    {
      const u16* Ap = A1 + m*K1 + kq*8;
      const u16* Wp = W1 + nb*K1 + kq*8;
      #pragma unroll 4
      for (int kc = 0; kc < K1; kc += 32){
        short8 a = *(const short8*)(Ap + kc);
        short8 b = *(const short8*)(Wp + kc);
        acc = __builtin_amdgcn_mfma_f32_16x16x32_bf16(a, b, acc, 0, 0, 0);
      }
    }
    {
      const u16* Ap = A2 + m*512 + kq*8;
      const u16* Wp = W2 + nb*512 + kq*8;
      #pragma unroll 4
      for (int kc = 0; kc < 512; kc += 32){
        short8 a = *(const short8*)(Ap + kc);
        short8 b = *(const short8*)(Wp + kc);
        acc = __builtin_amdgcn_mfma_f32_16x16x32_bf16(a, b, acc, 0, 0, 0);
      }
    }
    // C/D layout: row = kq*4 + r, col = lane&15
    const float bn = bias[nb];
    const int col = wave*16 + lrow;
    #pragma unroll
    for (int r = 0; r < 4; ++r) g[kq*4 + r][col] = acc[r] + bn;
    __syncthreads();
    float gi = g[bl][jl*4+0], gf = g[bl][jl*4+1];
    float gg = g[bl][jl*4+2], go = g[bl][jl*4+3];
    float iv = 1.f/(1.f + expf(-gi));
    float fv = 1.f/(1.f + expf(-gf));
    float ov = 1.f/(1.f + expf(-go));
    float gv = tanhf(gg);
    float cn = fv*creg + iv*gv;
    float hn = ov * tanhf(cn);
    creg = cn;
    hb[(mt*16 + bl)*512 + nt*16 + jl] = f2b(hn);
    return hn;
  };

  if (layer == 0){
    // encoder layer0: slot t in 0..255
    for (int t = 0; t < 256; ++t){
      waits(f0, 32u*t, f1, (t >= 1) ? 32u*(t-1) : 0u);
      step(p.Xb + t*4096, 32, p.Wx0,
           p.h0b + ((t+1)&1)*HB, p.W0hh, p.Bs, p.h0b + (t&1)*HB);
      release(f0);
    }
    // decoder layer0: slots s in 0..11
    for (int s = 0; s < 12; ++s){
      int ps = (s&1) ^ 1;
      waits(f0, 32u*(256+s), f1, 32u*(256+s));
      step(p.h1b + ps*HB, 512, p.Wd0ih,
           p.h0b + ps*HB, p.Wd0hh, p.Bs + 4096, p.h0b + (1-ps)*HB);
      release(f0);
    }
  } else {
    // encoder layer1: u in 0..255 (runs at slot u+1)
    for (int u = 0; u < 256; ++u){
      waits(f0, 32u*(u+1), f1, 32u*u);
      float hn = step(p.h0b + (u&1)*HB, 512, p.W1ih,
                      p.h1b + ((u+1)&1)*HB, p.W1hh, p.Bs + 2048, p.h1b + (u&1)*HB);
      if (u == 255){
        // heads from fp32 last
        __syncthreads();
        float* hs = (float*)g;
        hs[bl*16 + jl] = hn;
        __syncthreads();
        if (tid < 80){
          int b = tid / 5, d2 = tid % 5;
          float v = 0.f;
          if (d2 < 4){
            for (int j = 0; j < 16; ++j) v += hs[b*16 + j] * p.clsW[d2*512 + nt*16 + j];
            if (nt == 0) v += p.clsb[d2];
            atomicAdd(&p.out[9216 + (mt*16 + b)*4 + d2], v);
          } else {
            for (int j = 0; j < 16; ++j) v += hs[b*16 + j] * p.regW[nt*16 + j];
            if (nt == 0) v += p.regb[0];
            atomicAdd(&p.out[9728 + (mt*16 + b)], v);
          }
        }
        __syncthreads();
      }
      release(f1);
    }
    // decoder layer1 + forecast: s in 0..11
    for (int s = 0; s < 12; ++s){
      int ps = (s&1) ^ 1;
      waits(f0, 32u*(257+s), f1, 32u*(256+s));
      float hn = step(p.h0b + (1-ps)*HB, 512, p.Wd1ih,
                      p.h1b + ps*HB, p.Wd1hh, p.Bs + 6144, p.h1b + (1-ps)*HB);
      __syncthreads();
      float* hs = (float*)g;
      hs[bl*16 + jl] = hn;
      __syncthreads();
      if (tid < 96){
        int b = tid / 6, d2 = tid % 6;
        float v = 0.f;
        for (int j = 0; j < 16; ++j) v += hs[b*16 + j] * p.fcW[d2*512 + nt*16 + j];
        if (nt == 0) v += p.fcb[d2];
        atomicAdd(&p.out[(mt*16 + b)*72 + s*6 + d2], v);
      }
      __syncthreads();
      release(f1);
    }
  }
}

// ---------------- launcher ----------------

extern "C" void kernel_launch(void* const* d_in, const int* in_sizes, int n_in,
                              void* d_out, int out_size, void* d_ws, size_t ws_size,
                              hipStream_t stream){
  const float* x        = (const float*)d_in[0];
  const float* eWih0    = (const float*)d_in[1];
  const float* eWhh0    = (const float*)d_in[2];
  const float* ebih0    = (const float*)d_in[3];
  const float* ebhh0    = (const float*)d_in[4];
  const float* eWih1    = (const float*)d_in[5];
  const float* eWhh1    = (const float*)d_in[6];
  const float* ebih1    = (const float*)d_in[7];
  const float* ebhh1    = (const float*)d_in[8];
  const float* dWih0    = (const float*)d_in[9];
  const float* dWhh0    = (const float*)d_in[10];
  const float* dbih0    = (const float*)d_in[11];
  const float* dbhh0    = (const float*)d_in[12];
  const float* dWih1    = (const float*)d_in[13];
  const float* dWhh1    = (const float*)d_in[14];
  const float* dbih1    = (const float*)d_in[15];
  const float* dbhh1    = (const float*)d_in[16];
  const float* fcW      = (const float*)d_in[17];
  const float* fcb      = (const float*)d_in[18];
  const float* clsW     = (const float*)d_in[19];
  const float* clsb     = (const float*)d_in[20];
  const float* regW     = (const float*)d_in[21];
  const float* regb     = (const float*)d_in[22];
  float* out = (float*)d_out;

  uintptr_t base = (uintptr_t)d_ws;
  auto carve = [&](size_t n)->void*{
    void* p = (void*)base; base += (n + 255) & ~(size_t)255; return p;
  };
  u16* Wx0b  = (u16*)carve(2048*32*2);
  u16* We0hh = (u16*)carve(2048*512*2);
  u16* We1ih = (u16*)carve(2048*512*2);
  u16* We1hh = (u16*)carve(2048*512*2);
  u16* Wd0ih = (u16*)carve(2048*512*2);
  u16* Wd0hh = (u16*)carve(2048*512*2);
  u16* Wd1ih = (u16*)carve(2048*512*2);
  u16* Wd1hh = (u16*)carve(2048*512*2);
  float* Bs  = (float*)carve(4*2048*4);          // enc0, enc1, dec0, dec1
  u16* Xb    = (u16*)carve(256*128*32*2);
  u16* h0b   = (u16*)carve(2*128*512*2);         // ping-pong bf16 h
  u16* h1b   = (u16*)carve(2*128*512*2);
  unsigned* flags = (unsigned*)carve(64*4);

  // zero h-buffers + flags (contiguous, 256-aligned carves)
  hipMemsetAsync(h0b, 0, 2*128*512*2 + 2*128*512*2 + 256, stream);
  // out is accumulated via atomicAdd
  hipMemsetAsync(out, 0, (size_t)out_size*4, stream);

  reorder_w_k<<<4096,256,0,stream>>>(eWhh0, We0hh);
  reorder_w_k<<<4096,256,0,stream>>>(eWih1, We1ih);
  reorder_w_k<<<4096,256,0,stream>>>(eWhh1, We1hh);
  reorder_w_k<<<4096,256,0,stream>>>(dWih0, Wd0ih);
  reorder_w_k<<<4096,256,0,stream>>>(dWhh0, Wd0hh);
  reorder_w_k<<<4096,256,0,stream>>>(dWih1, Wd1ih);
  reorder_w_k<<<4096,256,0,stream>>>(dWhh1, Wd1hh);
  prep_wx0_k<<<256,256,0,stream>>>(eWih0, Wx0b);
  prep_bias_k<<<8,256,0,stream>>>(ebih0, ebhh0, Bs);
  prep_bias_k<<<8,256,0,stream>>>(ebih1, ebhh1, Bs + 2048);
  prep_bias_k<<<8,256,0,stream>>>(dbih0, dbhh0, Bs + 4096);
  prep_bias_k<<<8,256,0,stream>>>(dbih1, dbhh1, Bs + 6144);
  prep_x_k<<<4096,256,0,stream>>>(x, Xb);

  PK p;
  p.Xb = Xb; p.Wx0 = Wx0b; p.W0hh = We0hh; p.W1ih = We1ih; p.W1hh = We1hh;
  p.Wd0ih = Wd0ih; p.Wd0hh = Wd0hh; p.Wd1ih = Wd1ih; p.Wd1hh = Wd1hh;
  p.Bs = Bs; p.h0b = h0b; p.h1b = h1b; p.flags = flags;
  p.fcW = fcW; p.fcb = fcb; p.clsW = clsW; p.clsb = clsb;
  p.regW = regW; p.regb = regb; p.out = out;

  void* args[] = { &p };
  hipLaunchCooperativeKernel((const void*)persist_k, dim3(512), dim3(256),
                             args, 0, stream);
  (void)in_sizes; (void)n_in; (void)ws_size;
}